// Round 6
// baseline (393.729 us; speedup 1.0000x reference)
//
#include <hip/hip_runtime.h>

// LSTM: B=2048, T=512, D=1, H=50, OUT=3, fp32.
//
// R7: 2 tiles/wave. History:
//  R1-R4 (582..539us): VALU-issue-bound lane=unit designs.
//  R5 (381us disp): MFMA + LDS exchange; latency/barrier-bound.
//  R6 (291us disp): fused lane-local update, 1 barrier/step. MfmaUtil 11.6,
//     VALU 24 -> LDS-THROUGHPUT-bound: 13 waves x 4 redundant ds_read_b128
//     (52 reads x >=8 cyc = 416) + 261 conflict cyc/step ~= the whole
//     observed ~740-cyc step. All waves read IDENTICAL B-frags.
//
// R7 changes:
//  * NW=8 waves, each owns TWO 16-row gate tiles (units 8w..8w+7; 64>=50,
//    pad rows zeroed -> pad h stays exactly 0). Same 4 B-frag reads now
//    feed 12 MFMAs -> B-read instrs/step 52 -> 32.
//  * 3 accumulators/tile (Ah*Bh+bias, Ah*Bl, Al*Bh): dependent-MFMA chain
//    4 -> 2; the two tiles' chains interleave (ILP). 2 waves/SIMD hide
//    ds_read latency.
//  * Each lane updates 2 (unit,batch) pairs: u0=8w+hi, u1=u0+4; c0,c1,
//    h0,h1 in registers. 4 u16 h-writes/lane (hi/lo split). 1 barrier/step.
// Conventions unchanged from R5/R6 (verified):
//  A: row=lane&15 (permuted: gate=tr&3, unit), k=8*(lane>>4)+e (+32/K-step);
//  B: col=lane&15, same k; D: col=lane&15, row=4*(lane>>4)+reg.
//  hf[buf][hi/lo][batch=16][HS=72] u16, 144B rows.

#define BB 2048
#define TT 512
#define HH 50
#define NB 16            // batches per block (= MFMA cols)
#define NW 8             // waves; 2 tiles each -> 64 unit slots (50 real)
#define XP 513           // xs row stride (floats)
#define HS 72            // hf slot stride per batch row (u16; 144B rows)

typedef __attribute__((ext_vector_type(4))) float f32x4;
typedef __attribute__((ext_vector_type(8))) short s16x8;
typedef __attribute__((ext_vector_type(4))) int   i32x4;

__device__ __forceinline__ s16x8 pack_frag(int d0, int d1, int d2, int d3) {
    i32x4 v = {d0, d1, d2, d3};
    return __builtin_bit_cast(s16x8, v);
}

__device__ __forceinline__ float fast_sigmoid(float x) {
    float e = __builtin_amdgcn_exp2f(-1.4426950408889634f * x);
    return __builtin_amdgcn_rcpf(1.0f + e);
}

__device__ __forceinline__ float fast_tanh(float x) {
    float e = __builtin_amdgcn_exp2f(-2.8853900817779268f * x);  // e^{-2x}
    return __builtin_amdgcn_rcpf(1.0f + e) * 2.0f - 1.0f;
}

__global__ __launch_bounds__(NW * 64)
void lstm_fused2_kernel(const float* __restrict__ x,
                        const float* __restrict__ W_ih,
                        const float* __restrict__ W_hh,
                        const float* __restrict__ b_ih,
                        const float* __restrict__ b_hh,
                        const float* __restrict__ fc_w,
                        const float* __restrict__ fc_b,
                        float* __restrict__ out) {
    __shared__ float xs[NB * XP];                              // 32.8 KB
    __shared__ __align__(16) unsigned short hf[2][2][NB][HS];  // 9.2 KB
    __shared__ float hfin[NB][64];                             // 4 KB

    const int tid  = threadIdx.x;
    const int w    = tid >> 6;          // wave id, 0..7 (tiles 2w, 2w+1)
    const int lane = tid & 63;
    const int hi   = lane >> 4;
    const int bcol = lane & 15;         // batch column
    const int b0   = blockIdx.x * NB;

    // ---- stage x rows (coalesced) ----
    for (int idx = tid; idx < NB * TT; idx += NW * 64) {
        xs[(idx >> 9) * XP + (idx & 511)] = x[(b0 + (idx >> 9)) * TT + (idx & 511)];
    }
    // ---- zero h state (both buffers, incl. pad slots) ----
    for (int idx = tid; idx < (int)(sizeof(hf) / 4); idx += NW * 64) {
        ((unsigned*)hf)[idx] = 0;
    }

    // ---- A-fragments for 2 tiles: permuted rows (gate=tr&3, unit), hi/lo ----
    const int tr = bcol;                    // tile-row this lane supplies
    const int ga = tr & 3;                  // gate of this tile-row
    s16x8 Ah[2][2], Al[2][2];               // [tile][K-step]
    #pragma unroll
    for (int tt = 0; tt < 2; ++tt) {
        const int ua = 8 * w + 4 * tt + (tr >> 2);   // unit of this tile-row
        const bool arow_ok = (ua < HH);
        #pragma unroll
        for (int s = 0; s < 2; ++s) {
            int vhi[4], vlo[4];
            #pragma unroll
            for (int d = 0; d < 4; ++d) {
                const int k0 = 32 * s + 8 * hi + 2 * d;
                const int k1 = k0 + 1;
                const float w0 = (arow_ok && k0 < HH) ? W_hh[(ga * HH + ua) * HH + k0] : 0.0f;
                const float w1 = (arow_ok && k1 < HH) ? W_hh[(ga * HH + ua) * HH + k1] : 0.0f;
                const unsigned u0 = __float_as_uint(w0);
                const unsigned u1 = __float_as_uint(w1);
                vhi[d] = (int)((u1 & 0xffff0000u) | (u0 >> 16));
                const float r0 = w0 - __uint_as_float(u0 & 0xffff0000u);
                const float r1 = w1 - __uint_as_float(u1 & 0xffff0000u);
                vlo[d] = (int)((__float_as_uint(r1) & 0xffff0000u) |
                               (__float_as_uint(r0) >> 16));
            }
            Ah[tt][s] = pack_frag(vhi[0], vhi[1], vhi[2], vhi[3]);
            Al[tt][s] = pack_frag(vlo[0], vlo[1], vlo[2], vlo[3]);
        }
    }

    // ---- this lane's 2 (unit,batch) pairs and per-gate params ----
    const int u0 = 8 * w + hi;            // tile 2w
    const int u1 = u0 + 4;                // tile 2w+1
    float wih_[2][4], bs_[2][4];
    #pragma unroll
    for (int tt = 0; tt < 2; ++tt) {
        const int u = (tt == 0) ? u0 : u1;
        const bool ok = (u < HH);
        #pragma unroll
        for (int r = 0; r < 4; ++r) {
            wih_[tt][r] = ok ? W_ih[r * HH + u] : 0.0f;
            bs_[tt][r]  = ok ? (b_ih[r * HH + u] + b_hh[r * HH + u]) : 0.0f;
        }
    }

    // ---- LDS bases (u16 units). part stride 1152, buf stride 2304 ----
    const unsigned short* rb = &hf[0][0][bcol][8 * hi];   // B-frag reads
    unsigned short*       wb = &hf[0][0][bcol][u0];       // h writes (u1=u0+4)

    float c0 = 0.0f, c1 = 0.0f, h0 = 0.0f, h1 = 0.0f;

    __syncthreads();

    // One step: read buf CB, write buf 1-CB, one barrier.
#define STEP(CB, T) { \
        const s16x8 Bh0 = *(const s16x8*)(rb + (CB) * 2304); \
        const s16x8 Bh1 = *(const s16x8*)(rb + (CB) * 2304 + 32); \
        const s16x8 Bl0 = *(const s16x8*)(rb + (CB) * 2304 + 1152); \
        const s16x8 Bl1 = *(const s16x8*)(rb + (CB) * 2304 + 1152 + 32); \
        const float xv = xs[bcol * XP + (T)]; \
        f32x4 aH0, aH1, aM0, aM1, aL0, aL1; \
        _Pragma("unroll") \
        for (int r = 0; r < 4; ++r) { \
            aH0[r] = fmaf(xv, wih_[0][r], bs_[0][r]); \
            aH1[r] = fmaf(xv, wih_[1][r], bs_[1][r]); \
            aM0[r] = 0.0f; aM1[r] = 0.0f; aL0[r] = 0.0f; aL1[r] = 0.0f; } \
        aH0 = __builtin_amdgcn_mfma_f32_16x16x32_bf16(Ah[0][0], Bh0, aH0, 0, 0, 0); \
        aH1 = __builtin_amdgcn_mfma_f32_16x16x32_bf16(Ah[1][0], Bh0, aH1, 0, 0, 0); \
        aM0 = __builtin_amdgcn_mfma_f32_16x16x32_bf16(Ah[0][0], Bl0, aM0, 0, 0, 0); \
        aM1 = __builtin_amdgcn_mfma_f32_16x16x32_bf16(Ah[1][0], Bl0, aM1, 0, 0, 0); \
        aL0 = __builtin_amdgcn_mfma_f32_16x16x32_bf16(Al[0][0], Bh0, aL0, 0, 0, 0); \
        aL1 = __builtin_amdgcn_mfma_f32_16x16x32_bf16(Al[1][0], Bh0, aL1, 0, 0, 0); \
        aH0 = __builtin_amdgcn_mfma_f32_16x16x32_bf16(Ah[0][1], Bh1, aH0, 0, 0, 0); \
        aH1 = __builtin_amdgcn_mfma_f32_16x16x32_bf16(Ah[1][1], Bh1, aH1, 0, 0, 0); \
        aM0 = __builtin_amdgcn_mfma_f32_16x16x32_bf16(Ah[0][1], Bl1, aM0, 0, 0, 0); \
        aM1 = __builtin_amdgcn_mfma_f32_16x16x32_bf16(Ah[1][1], Bl1, aM1, 0, 0, 0); \
        aL0 = __builtin_amdgcn_mfma_f32_16x16x32_bf16(Al[0][1], Bh1, aL0, 0, 0, 0); \
        aL1 = __builtin_amdgcn_mfma_f32_16x16x32_bf16(Al[1][1], Bh1, aL1, 0, 0, 0); \
        const float iv0 = fast_sigmoid(aH0[0] + aM0[0] + aL0[0]); \
        const float fv0 = fast_sigmoid(aH0[1] + aM0[1] + aL0[1]); \
        const float gv0 = fast_tanh   (aH0[2] + aM0[2] + aL0[2]); \
        const float ov0 = fast_sigmoid(aH0[3] + aM0[3] + aL0[3]); \
        const float iv1 = fast_sigmoid(aH1[0] + aM1[0] + aL1[0]); \
        const float fv1 = fast_sigmoid(aH1[1] + aM1[1] + aL1[1]); \
        const float gv1 = fast_tanh   (aH1[2] + aM1[2] + aL1[2]); \
        const float ov1 = fast_sigmoid(aH1[3] + aM1[3] + aL1[3]); \
        c0 = fmaf(fv0, c0, iv0 * gv0); \
        c1 = fmaf(fv1, c1, iv1 * gv1); \
        h0 = ov0 * fast_tanh(c0); \
        h1 = ov1 * fast_tanh(c1); \
        const unsigned hu0 = __float_as_uint(h0); \
        const unsigned hu1 = __float_as_uint(h1); \
        wb[(1 - (CB)) * 2304]     = (unsigned short)(hu0 >> 16); \
        wb[(1 - (CB)) * 2304 + 4] = (unsigned short)(hu1 >> 16); \
        const float rs0 = h0 - __uint_as_float(hu0 & 0xffff0000u); \
        const float rs1 = h1 - __uint_as_float(hu1 & 0xffff0000u); \
        wb[(1 - (CB)) * 2304 + 1152]     = (unsigned short)(__float_as_uint(rs0) >> 16); \
        wb[(1 - (CB)) * 2304 + 1152 + 4] = (unsigned short)(__float_as_uint(rs1) >> 16); \
        __syncthreads(); }

    #pragma unroll 1
    for (int t = 0; t < TT; t += 2) {
        STEP(0, t)
        STEP(1, t + 1)
    }
#undef STEP

    // ---- epilogue: h_T dot fc_w (once) ----
    hfin[bcol][u0] = h0;
    hfin[bcol][u1] = h1;
    __syncthreads();
    if (tid < NB * 3) {
        const int b = tid / 3, o = tid % 3;
        float s = fc_b[o];
        for (int uu = 0; uu < HH; ++uu)
            s = fmaf(hfin[b][uu], fc_w[o * HH + uu], s);
        out[(b0 + b) * 3 + o] = s;
    }
}

extern "C" void kernel_launch(void* const* d_in, const int* in_sizes, int n_in,
                              void* d_out, int out_size, void* d_ws, size_t ws_size,
                              hipStream_t stream) {
    const float* x    = (const float*)d_in[0];
    const float* W_ih = (const float*)d_in[1];
    const float* W_hh = (const float*)d_in[2];
    const float* b_ih = (const float*)d_in[3];
    const float* b_hh = (const float*)d_in[4];
    const float* fc_w = (const float*)d_in[5];
    const float* fc_b = (const float*)d_in[6];
    float* out = (float*)d_out;

    dim3 grid(BB / NB);      // 128 blocks
    dim3 block(NW * 64);     // 512 threads = 8 waves
    lstm_fused2_kernel<<<grid, block, 0, stream>>>(x, W_ih, W_hh, b_ih, b_hh,
                                                   fc_w, fc_b, out);
}

// Round 7
// 319.440 us; speedup vs baseline: 1.2326x; 1.2326x over previous
//
#include <hip/hip_runtime.h>

// LSTM: B=2048, T=512, D=1, H=50, OUT=3, fp32.
//
// R8: fp16 2-term. History:
//  R1-R4 (582..539us): VALU-issue-bound lane=unit designs. absmax 0.0
//     with exact fp32 matmul + fast activations -> ALL of R5-R7's 4.9e-4
//     came from the bf16 hi/lo split scheme (per-step ~1.5e-5 rel, x33
//     amplification over 512 steps).
//  R5 381 / R6 291 / R7 345 (dispatch us): MFMA designs. Model that fits
//     all three: step = read-burst drain (NW*reads*8 cyc + conflicts)
//     + MFMA + back-loaded VALU tail stacked per SIMD (~400 cyc/SIMD,
//     ~fixed). R6 (NW=13) hides the tail best; R7 (NW=8, 2x tail/wave)
//     exposed it. Remaining lever: the 64B/lane/step dynamic bytes of
//     the 3-term bf16 split.
//
// R8 changes vs R6:
//  * fp16 2-term: W = Wh(fp16 RTN) + 2^-11 * Wl' (Wl' = RTN((W-Wh)*2^11),
//    scaled to avoid fp16 subnormal flush; |W|<=0.144 -> Wl' normal).
//    h stored as ONE fp16 RTN array. Gates = Wh*H + 2^-11*(Wl'*H).
//    Error = h quantization only (2^-12 rel/step) -> absmax ~8e-3 pred.
//  * B-frag reads/wave 4 -> 2 (burst 416 -> 208 cyc), MFMAs 6 -> 4/tile,
//    h-writes 2 -> 1 b16/lane, shorter pack tail (1 cvt).
//  * Everything else identical to R6: 13 waves x 1 tile, permuted A rows
//    (gate=tr&3, unit=4w+tr>>2) so each lane's acc[0..3] = 4 gates of its
//    (unit,batch); lane-local c/h; ONE barrier/step; double-buffered h.
// Layout conventions (R5/R6/R7-verified):
//  A: row=lane&15 (permuted), k=8*(lane>>4)+e (+32/K-step); B: col=lane&15,
//  same k; D: col=lane&15, row=4*(lane>>4)+reg.

#define BB 2048
#define TT 512
#define HH 50
#define NB 16            // batches per block (= MFMA cols)
#define NW 13            // waves: 13 tiles x 4 units = 52 >= 50 units
#define XP 513           // xs row stride (floats)
#define HS 72            // hf unit-slot stride per batch row (u16; 144B)
#define LO_SCALE  2048.0f            // 2^11
#define LO_ISCALE 0.00048828125f     // 2^-11

typedef __attribute__((ext_vector_type(4))) float    f32x4;
typedef __attribute__((ext_vector_type(8))) _Float16 f16x8;

__device__ __forceinline__ float fast_sigmoid(float x) {
    float e = __builtin_amdgcn_exp2f(-1.4426950408889634f * x);
    return __builtin_amdgcn_rcpf(1.0f + e);
}

__device__ __forceinline__ float fast_tanh(float x) {
    float e = __builtin_amdgcn_exp2f(-2.8853900817779268f * x);  // e^{-2x}
    return __builtin_amdgcn_rcpf(1.0f + e) * 2.0f - 1.0f;
}

__global__ __launch_bounds__(NW * 64)
void lstm_f16_kernel(const float* __restrict__ x,
                     const float* __restrict__ W_ih,
                     const float* __restrict__ W_hh,
                     const float* __restrict__ b_ih,
                     const float* __restrict__ b_hh,
                     const float* __restrict__ fc_w,
                     const float* __restrict__ fc_b,
                     float* __restrict__ out) {
    __shared__ float xs[NB * XP];                           // 32.8 KB
    __shared__ __align__(16) unsigned short hf[2][NB][HS];  // 4.6 KB (fp16 h)
    __shared__ float hfin[NB][64];                          // 4 KB

    const int tid  = threadIdx.x;
    const int w    = tid >> 6;          // wave id = tile id, 0..12
    const int lane = tid & 63;
    const int hi   = lane >> 4;
    const int bcol = lane & 15;         // batch column
    const int b0   = blockIdx.x * NB;

    // ---- stage x rows (coalesced) ----
    for (int idx = tid; idx < NB * TT; idx += NW * 64) {
        xs[(idx >> 9) * XP + (idx & 511)] = x[(b0 + (idx >> 9)) * TT + (idx & 511)];
    }
    // ---- zero h state (both buffers incl. pad slots; fp16 0 = 0 bits) ----
    for (int idx = tid; idx < (int)(sizeof(hf) / 4); idx += NW * 64) {
        ((unsigned*)hf)[idx] = 0;
    }

    // ---- A-fragments: permuted rows (gate=tr&3, unit=4w+tr>>2), fp16 ----
    const int tr = bcol;                    // tile-row this lane supplies
    const int ga = tr & 3;                  // gate of this tile-row
    const int ua = 4 * w + (tr >> 2);       // unit of this tile-row
    const bool arow_ok = (ua < HH);
    f16x8 Ah0, Ah1, Al0, Al1;
    #pragma unroll
    for (int s = 0; s < 2; ++s) {
        #pragma unroll
        for (int e = 0; e < 8; ++e) {
            const int k = 32 * s + 8 * hi + e;
            const float wv = (arow_ok && k < HH) ? W_hh[(ga * HH + ua) * HH + k] : 0.0f;
            const _Float16 whv = (_Float16)wv;                       // RTN
            const _Float16 wlv = (_Float16)((wv - (float)whv) * LO_SCALE);
            if (s == 0) { Ah0[e] = whv; Al0[e] = wlv; }
            else        { Ah1[e] = whv; Al1[e] = wlv; }
        }
    }

    // ---- this lane's (unit, batch) pair and per-gate params ----
    const int  u    = 4 * w + hi;           // unit owned by this lane
    const bool u_ok = (u < HH);
    float wih_[4], bs_[4];
    #pragma unroll
    for (int r = 0; r < 4; ++r) {           // gate r rows: r*HH + u
        wih_[r] = u_ok ? W_ih[r * HH + u] : 0.0f;
        bs_[r]  = u_ok ? (b_ih[r * HH + u] + b_hh[r * HH + u]) : 0.0f;
    }

    // ---- LDS bases (u16 units). buf stride = NB*HS = 1152 ----
    const unsigned short* rb = &hf[0][bcol][8 * hi];   // B-frag reads
    unsigned short*       wb = &hf[0][bcol][u];        // h write

    float c = 0.0f, hcur = 0.0f;

    __syncthreads();

    // One step: read buf CB, write buf 1-CB, one barrier.
#define STEP(CB, T) { \
        const f16x8 B0 = *(const f16x8*)(rb + (CB) * 1152); \
        const f16x8 B1 = *(const f16x8*)(rb + (CB) * 1152 + 32); \
        const float xv = xs[bcol * XP + (T)]; \
        f32x4 acc, acc2; \
        _Pragma("unroll") \
        for (int r = 0; r < 4; ++r) { acc[r] = fmaf(xv, wih_[r], bs_[r]); acc2[r] = 0.0f; } \
        acc  = __builtin_amdgcn_mfma_f32_16x16x32_f16(Ah0, B0, acc,  0, 0, 0); \
        acc  = __builtin_amdgcn_mfma_f32_16x16x32_f16(Ah1, B1, acc,  0, 0, 0); \
        acc2 = __builtin_amdgcn_mfma_f32_16x16x32_f16(Al0, B0, acc2, 0, 0, 0); \
        acc2 = __builtin_amdgcn_mfma_f32_16x16x32_f16(Al1, B1, acc2, 0, 0, 0); \
        const float v0 = fmaf(acc2[0], LO_ISCALE, acc[0]); \
        const float v1 = fmaf(acc2[1], LO_ISCALE, acc[1]); \
        const float v2 = fmaf(acc2[2], LO_ISCALE, acc[2]); \
        const float v3 = fmaf(acc2[3], LO_ISCALE, acc[3]); \
        const float iv = fast_sigmoid(v0); \
        const float fv = fast_sigmoid(v1); \
        const float gv = fast_tanh   (v2); \
        const float ov = fast_sigmoid(v3); \
        c    = fmaf(fv, c, iv * gv); \
        hcur = ov * fast_tanh(c); \
        const _Float16 hq = (_Float16)hcur;                 /* RTN */ \
        wb[(1 - (CB)) * 1152] = __builtin_bit_cast(unsigned short, hq); \
        __syncthreads(); }

    #pragma unroll 1
    for (int t = 0; t < TT; t += 2) {
        STEP(0, t)
        STEP(1, t + 1)
    }
#undef STEP

    // ---- epilogue: h_T dot fc_w (once) ----
    hfin[bcol][u] = hcur;           // u <= 51 < 64; pad units unused below
    __syncthreads();
    if (tid < NB * 3) {
        const int b = tid / 3, o = tid % 3;
        float s = fc_b[o];
        for (int uu = 0; uu < HH; ++uu)
            s = fmaf(hfin[b][uu], fc_w[o * HH + uu], s);
        out[(b0 + b) * 3 + o] = s;
    }
}

extern "C" void kernel_launch(void* const* d_in, const int* in_sizes, int n_in,
                              void* d_out, int out_size, void* d_ws, size_t ws_size,
                              hipStream_t stream) {
    const float* x    = (const float*)d_in[0];
    const float* W_ih = (const float*)d_in[1];
    const float* W_hh = (const float*)d_in[2];
    const float* b_ih = (const float*)d_in[3];
    const float* b_hh = (const float*)d_in[4];
    const float* fc_w = (const float*)d_in[5];
    const float* fc_b = (const float*)d_in[6];
    float* out = (float*)d_out;

    dim3 grid(BB / NB);      // 128 blocks
    dim3 block(NW * 64);     // 832 threads = 13 waves
    lstm_f16_kernel<<<grid, block, 0, stream>>>(x, W_ih, W_hh, b_ih, b_hh,
                                                fc_w, fc_b, out);
}

// Round 8
// 318.441 us; speedup vs baseline: 1.2364x; 1.0031x over previous
//
#include <hip/hip_runtime.h>

// LSTM: B=2048, T=512, D=1, H=50, OUT=3, fp32.
//
// R9: merged-rcp update + masked upper read. History:
//  R1-R4 (582..539us): VALU-issue-bound lane=unit designs.
//  R5 381 / R6 291 / R7 345 / R8 268.6 (dispatch us): MFMA designs.
//  R8 counters: MfmaUtil 8.3, VALU 24.5, conflicts 8.6e6. Step ~680cyc =
//  LDS burst ~340 (26 b128 reads + conflicts; serialized post-barrier,
//  VALUs idle - lockstep) + VALU ~167/SIMD (half = 10 quarter-rate trans
//  ops/update) + MFMA/barrier slop. Wall = 512 x step latency (128 CUs
//  already idle; only per-CU per-step cost matters).
//
// R9 changes vs R8 (same structure: NW=13 x 16-row tiles, permuted A rows,
// lane-local c/h, fp16 2-term W, fp16 h, 1 barrier/step):
//  * Merged-reciprocal update: c' = N/D with N = c*P1*PG + MG*P2,
//    D = P1*P2*PG (ONE rcp for i,f,g); h = (1-C5)/((1+C5)*P4) (ONE rcp
//    merges o and tanh(c')). Trans 10 -> 7 per update. Algebraically
//    identical to sigmoid/tanh form -> absmax unchanged. |preact|<=~8
//    -> D <= 2^26, no overflow. Pad lanes: v=0 -> MG=0, c stays 0, h=0.
//  * hi=3 lanes skip the upper B-frag read (k=56..63 is always zero:
//    units >=52 never written) -> exec-masked, saves 1/8 of read bytes.
// Layout conventions (R5-R8-verified):
//  A: row=lane&15 (permuted: gate=tr&3, unit=4w+tr>>2), k=8*(lane>>4)+e
//  (+32/K-step); B: col=lane&15, same k; D: col=lane&15, row=4*(lane>>4)+reg.

#define BB 2048
#define TT 512
#define HH 50
#define NB 16            // batches per block (= MFMA cols)
#define NW 13            // waves: 13 tiles x 4 units = 52 >= 50 units
#define XP 513           // xs row stride (floats)
#define HS 72            // hf unit-slot stride per batch row (u16; 144B)
#define LO_SCALE  2048.0f            // 2^11
#define LO_ISCALE 0.00048828125f     // 2^-11
#define L1 -1.4426950408889634f      // -log2(e)
#define L2 -2.8853900817779268f      // -2*log2(e)

typedef __attribute__((ext_vector_type(4))) float    f32x4;
typedef __attribute__((ext_vector_type(8))) _Float16 f16x8;

__global__ __launch_bounds__(NW * 64)
void lstm_r9_kernel(const float* __restrict__ x,
                    const float* __restrict__ W_ih,
                    const float* __restrict__ W_hh,
                    const float* __restrict__ b_ih,
                    const float* __restrict__ b_hh,
                    const float* __restrict__ fc_w,
                    const float* __restrict__ fc_b,
                    float* __restrict__ out) {
    __shared__ float xs[NB * XP];                           // 32.8 KB
    __shared__ __align__(16) unsigned short hf[2][NB][HS];  // 4.6 KB (fp16 h)
    __shared__ float hfin[NB][64];                          // 4 KB

    const int tid  = threadIdx.x;
    const int w    = tid >> 6;          // wave id = tile id, 0..12
    const int lane = tid & 63;
    const int hi   = lane >> 4;
    const int bcol = lane & 15;         // batch column
    const int b0   = blockIdx.x * NB;

    // ---- stage x rows (coalesced) ----
    for (int idx = tid; idx < NB * TT; idx += NW * 64) {
        xs[(idx >> 9) * XP + (idx & 511)] = x[(b0 + (idx >> 9)) * TT + (idx & 511)];
    }
    // ---- zero h state (both buffers incl. pad slots; fp16 0 = 0 bits) ----
    for (int idx = tid; idx < (int)(sizeof(hf) / 4); idx += NW * 64) {
        ((unsigned*)hf)[idx] = 0;
    }

    // ---- A-fragments: permuted rows (gate=tr&3, unit=4w+tr>>2), fp16 ----
    const int tr = bcol;                    // tile-row this lane supplies
    const int ga = tr & 3;                  // gate of this tile-row
    const int ua = 4 * w + (tr >> 2);       // unit of this tile-row
    const bool arow_ok = (ua < HH);
    f16x8 Ah0, Ah1, Al0, Al1;
    #pragma unroll
    for (int s = 0; s < 2; ++s) {
        #pragma unroll
        for (int e = 0; e < 8; ++e) {
            const int k = 32 * s + 8 * hi + e;
            const float wv = (arow_ok && k < HH) ? W_hh[(ga * HH + ua) * HH + k] : 0.0f;
            const _Float16 whv = (_Float16)wv;                       // RTN
            const _Float16 wlv = (_Float16)((wv - (float)whv) * LO_SCALE);
            if (s == 0) { Ah0[e] = whv; Al0[e] = wlv; }
            else        { Ah1[e] = whv; Al1[e] = wlv; }
        }
    }

    // ---- this lane's (unit, batch) pair and per-gate params ----
    const int  u    = 4 * w + hi;           // unit owned by this lane
    const bool u_ok = (u < HH);
    float wih_[4], bs_[4];
    #pragma unroll
    for (int r = 0; r < 4; ++r) {           // gate r rows: r*HH + u
        wih_[r] = u_ok ? W_ih[r * HH + u] : 0.0f;
        bs_[r]  = u_ok ? (b_ih[r * HH + u] + b_hh[r * HH + u]) : 0.0f;
    }

    // ---- LDS bases (u16 units). buf stride = NB*HS = 1152 ----
    const unsigned short* rb = &hf[0][bcol][8 * hi];   // B-frag reads
    unsigned short*       wb = &hf[0][bcol][u];        // h write

    float c = 0.0f, hcur = 0.0f;

    __syncthreads();

    // One step: read buf CB, write buf 1-CB, one barrier.
#define STEP(CB, T) { \
        const f16x8 B0 = *(const f16x8*)(rb + (CB) * 1152); \
        f16x8 B1 = {};  /* hi=3: k=56..63 is identically zero */ \
        if (hi < 3) B1 = *(const f16x8*)(rb + (CB) * 1152 + 32); \
        const float xv = xs[bcol * XP + (T)]; \
        f32x4 acc, acc2; \
        _Pragma("unroll") \
        for (int r = 0; r < 4; ++r) { acc[r] = fmaf(xv, wih_[r], bs_[r]); acc2[r] = 0.0f; } \
        acc  = __builtin_amdgcn_mfma_f32_16x16x32_f16(Ah0, B0, acc,  0, 0, 0); \
        acc  = __builtin_amdgcn_mfma_f32_16x16x32_f16(Ah1, B1, acc,  0, 0, 0); \
        acc2 = __builtin_amdgcn_mfma_f32_16x16x32_f16(Al0, B0, acc2, 0, 0, 0); \
        acc2 = __builtin_amdgcn_mfma_f32_16x16x32_f16(Al1, B1, acc2, 0, 0, 0); \
        const float v0 = fmaf(acc2[0], LO_ISCALE, acc[0]); \
        const float v1 = fmaf(acc2[1], LO_ISCALE, acc[1]); \
        const float v2 = fmaf(acc2[2], LO_ISCALE, acc[2]); \
        const float v3 = fmaf(acc2[3], LO_ISCALE, acc[3]); \
        const float E1 = __builtin_amdgcn_exp2f(L1 * v0);   /* i */ \
        const float E2 = __builtin_amdgcn_exp2f(L1 * v1);   /* f */ \
        const float G  = __builtin_amdgcn_exp2f(L2 * v2);   /* g (tanh) */ \
        const float E4 = __builtin_amdgcn_exp2f(L1 * v3);   /* o */ \
        const float P1 = 1.0f + E1, P2 = 1.0f + E2; \
        const float PG = 1.0f + G,  P4 = 1.0f + E4; \
        const float MG = 1.0f - G; \
        const float N  = fmaf(c * P1, PG, MG * P2); \
        const float D  = (P1 * P2) * PG; \
        c = N * __builtin_amdgcn_rcpf(D); \
        const float C5 = __builtin_amdgcn_exp2f(L2 * c); \
        const float Q  = (1.0f + C5) * P4; \
        hcur = (1.0f - C5) * __builtin_amdgcn_rcpf(Q); \
        const _Float16 hq = (_Float16)hcur;                 /* RTN */ \
        wb[(1 - (CB)) * 1152] = __builtin_bit_cast(unsigned short, hq); \
        __syncthreads(); }

    #pragma unroll 1
    for (int t = 0; t < TT; t += 2) {
        STEP(0, t)
        STEP(1, t + 1)
    }
#undef STEP

    // ---- epilogue: h_T dot fc_w (once) ----
    hfin[bcol][u] = hcur;           // u <= 51 < 64; pad units unused below
    __syncthreads();
    if (tid < NB * 3) {
        const int b = tid / 3, o = tid % 3;
        float s = fc_b[o];
        for (int uu = 0; uu < HH; ++uu)
            s = fmaf(hfin[b][uu], fc_w[o * HH + uu], s);
        out[(b0 + b) * 3 + o] = s;
    }
}

extern "C" void kernel_launch(void* const* d_in, const int* in_sizes, int n_in,
                              void* d_out, int out_size, void* d_ws, size_t ws_size,
                              hipStream_t stream) {
    const float* x    = (const float*)d_in[0];
    const float* W_ih = (const float*)d_in[1];
    const float* W_hh = (const float*)d_in[2];
    const float* b_ih = (const float*)d_in[3];
    const float* b_hh = (const float*)d_in[4];
    const float* fc_w = (const float*)d_in[5];
    const float* fc_b = (const float*)d_in[6];
    float* out = (float*)d_out;

    dim3 grid(BB / NB);      // 128 blocks
    dim3 block(NW * 64);     // 832 threads = 13 waves
    lstm_r9_kernel<<<grid, block, 0, stream>>>(x, W_ih, W_hh, b_ih, b_hh,
                                               fc_w, fc_b, out);
}